// Round 1
// 70.645 us; speedup vs baseline: 1.0030x; 1.0030x over previous
//
#include <hip/hip_runtime.h>
#include <hip/hip_bf16.h>
#include <math.h>

// FGN layer, R9 — two-pass byte-reduction:
//   Pass 1 (fgn_prep): convert the 5 MFMA operand streams to bf16 ONCE
//     (XB=x, X2B=x^2, WB=w, G1=-2*c*s^2, G2=s^2; s=min(ic,1e8)) and
//     precompute cz[n] = sum_k c^2 s^2.  4 MB fp32 -> 2.5 MB bf16 in d_ws.
//   Pass 2 (fgn_main): 64m x 32n tile, 8 waves (4m x 2n quadrants),
//     global_load_lds(16B) direct staging of packed bf16 (no VGPR round
//     trip, no in-loop conversion VALU), double-buffered LDS, 1 barrier
//     per K-step.  Staged global reads: 134 MB (R8) -> 57 MB.
// Rationale: R8's ~30 us share of dur_us is redundant fp32 panel re-reads
// billed at HBM rate (the harness's 256 MiB poison evicts L2+L3 every
// iteration); compute pipes were proven idle by R7's ablations.
// LDS swizzle: linear dest for global_load_lds, XOR ((row&7)<<4) applied
// on the per-lane global SOURCE and again on the ds_read address
// (both-sides involution); <=2-way bank alias within each quarter-wave.

typedef __attribute__((ext_vector_type(8))) short short8;
typedef __attribute__((ext_vector_type(4))) float floatx4;

#define MFMA __builtin_amdgcn_mfma_f32_16x16x32_bf16

#define GLDS16(g, l) __builtin_amdgcn_global_load_lds(                      \
    (const __attribute__((address_space(1))) void*)(g),                     \
    (__attribute__((address_space(3))) void*)(l), 16, 0, 0)

__device__ __forceinline__ unsigned pkbf(float a, float b) {
    union { __hip_bfloat162 h; unsigned u; } v;
    v.h = __float22bfloat162_rn(make_float2(a, b));
    return v.u;
}

// ---------------- pass 1: pack operands to bf16, compute cz ----------------
__global__ __launch_bounds__(256)
void fgn_prep(const float* __restrict__ X, const float* __restrict__ W,
              const float* __restrict__ C, const float* __restrict__ IC,
              unsigned short* __restrict__ XB, unsigned short* __restrict__ X2B,
              unsigned short* __restrict__ WB, unsigned short* __restrict__ G1,
              unsigned short* __restrict__ G2, float* __restrict__ CZ)
{
    const int t = threadIdx.x, w = t >> 6, l = t & 63;
    const int b = blockIdx.x;
    if (b < 256) {                       // B-side rows: one wave per z-row
        const int z = b * 4 + w;
        const int o = z * 256 + l * 4;   // 64 lanes x float4 = 256 k
        const float4 c4 = *(const float4*)&C[o];
        const float4 i4 = *(const float4*)&IC[o];
        const float4 w4 = *(const float4*)&W[o];
        float s;
        s = fminf(i4.x, 1e8f); const float q0 = s * s;
        s = fminf(i4.y, 1e8f); const float q1 = s * s;
        s = fminf(i4.z, 1e8f); const float q2 = s * s;
        s = fminf(i4.w, 1e8f); const float q3 = s * s;
        float czp = c4.x*c4.x*q0 + c4.y*c4.y*q1 + c4.z*c4.z*q2 + c4.w*c4.w*q3;
        *(uint2*)&WB[o] = make_uint2(pkbf(w4.x, w4.y), pkbf(w4.z, w4.w));
        *(uint2*)&G1[o] = make_uint2(pkbf(-2.f*c4.x*q0, -2.f*c4.y*q1),
                                     pkbf(-2.f*c4.z*q2, -2.f*c4.w*q3));
        *(uint2*)&G2[o] = make_uint2(pkbf(q0, q1), pkbf(q2, q3));
        #pragma unroll
        for (int off = 32; off; off >>= 1) czp += __shfl_down(czp, off);
        if (l == 0) CZ[z] = czp;
    } else {                             // X-side rows
        const int m = (b - 256) * 4 + w;
        const int o = m * 256 + l * 4;
        const float4 x4 = *(const float4*)&X[o];
        *(uint2*)&XB[o]  = make_uint2(pkbf(x4.x, x4.y), pkbf(x4.z, x4.w));
        *(uint2*)&X2B[o] = make_uint2(pkbf(x4.x*x4.x, x4.y*x4.y),
                                      pkbf(x4.z*x4.z, x4.w*x4.w));
    }
}

// ---------------- pass 2: fused bf16 GEMM + gating ----------------
// LDS buffer layout (bytes): Ax[64][64bf16]=8K, Ax2=8K, Bw[32][64]=4K, Bg1=4K, Bg2=4K
#define L_AX   0
#define L_AX2  8192
#define L_BW   16384
#define L_BG1  20480
#define L_BG2  24576
#define L_BUF  28672     // 28 KB per buffer, x2 = 56 KB -> 2 blocks/CU

__global__ __launch_bounds__(512)
void fgn_main(const unsigned short* __restrict__ XB, const unsigned short* __restrict__ X2B,
              const unsigned short* __restrict__ WB, const unsigned short* __restrict__ G1,
              const unsigned short* __restrict__ G2, const float* __restrict__ Bias,
              const float* __restrict__ CZ, float* __restrict__ Out)
{
    __shared__ __align__(16) char lds[2 * L_BUF];

    // XCD-aware swizzle (same heuristic as R8): xcd = b&7 owns 4 n-tiles
    const int b  = blockIdx.x;               // 0..511
    const int n0 = ((b & 7) + 8 * ((b >> 3) & 3)) * 32;   // n-tile 0..31
    const int m0 = (b >> 5) * 64;                         // m-tile 0..15

    const int t    = threadIdx.x;
    const int w    = t >> 6;
    const int lane = t & 63;
    const int r    = lane & 15;
    const int q    = lane >> 4;
    const int mt   = w & 3;                  // m-quadrant 0..3
    const int nt   = w >> 2;                 // n-quadrant 0..1

    // staging: LDS gets linear (global_load_lds: wave-uniform base + lane*16);
    // swizzle applied on the per-lane global source, undone on ds_read.
    const int rt = t >> 3;                   // A: row 0..63 ; B (t<256): row 0..31
    const int cs = ((t & 7) << 4) ^ ((rt & 7) << 4);   // swizzled byte chunk in row
    const int srcA = (m0 + rt) * 512 + cs;   // byte offset into 512 B bf16 rows
    const int srcB = (n0 + rt) * 512 + cs;   // valid for t < 256 only
    const int wbase = (t >> 6) << 10;        // wave-uniform 1 KB segment

    floatx4 zero = {0.f, 0.f, 0.f, 0.f};
    floatx4 accL = zero;
    floatx4 accG = zero;

    auto STAGE = [&](int buf, int k0) {
        char* L = lds + buf * L_BUF;
        const int kb = k0 << 1;              // byte offset of k-chunk in row
        GLDS16((const char*)XB  + srcA + kb, L + L_AX  + wbase);
        GLDS16((const char*)X2B + srcA + kb, L + L_AX2 + wbase);
        if (t < 256) {                       // waves 0..3 stage the 4 KB B-tiles
            GLDS16((const char*)WB + srcB + kb, L + L_BW  + wbase);
            GLDS16((const char*)G1 + srcB + kb, L + L_BG1 + wbase);
            GLDS16((const char*)G2 + srcB + kb, L + L_BG2 + wbase);
        }
    };

    const int arow = mt * 16 + r;
    const int brow = nt * 16 + r;
    auto COMPUTE = [&](int buf) {
        const char* L = lds + buf * L_BUF;
        #pragma unroll
        for (int kk = 0; kk < 2; ++kk) {
            const int ca = kk * 64 + q * 16;                     // byte chunk
            const int ao = arow * 128 + (ca ^ ((arow & 7) << 4));
            const int bo = brow * 128 + (ca ^ ((brow & 7) << 4));
            short8 a0 = *(const short8*)(L + L_AX  + ao);
            short8 a2 = *(const short8*)(L + L_AX2 + ao);
            short8 bw = *(const short8*)(L + L_BW  + bo);
            short8 b1 = *(const short8*)(L + L_BG1 + bo);
            short8 b2 = *(const short8*)(L + L_BG2 + bo);
            accL = MFMA(a0, bw, accL, 0, 0, 0);
            accG = MFMA(a0, b1, accG, 0, 0, 0);
            accG = MFMA(a2, b2, accG, 0, 0, 0);
        }
    };

    STAGE(0, 0);
    asm volatile("s_waitcnt vmcnt(0)" ::: "memory");
    __syncthreads();

    int cur = 0;
    #pragma unroll
    for (int k0 = 0; k0 < 256; k0 += 64) {
        if (k0 + 64 < 256) STAGE(cur ^ 1, k0 + 64);   // issue next tile first
        COMPUTE(cur);
        if (k0 + 64 < 256) {
            asm volatile("s_waitcnt vmcnt(0)" ::: "memory");
            __syncthreads();
            cur ^= 1;
        }
    }

    // epilogue straight from registers; cz comes precomputed from pass 1
    const int   n    = n0 + nt * 16 + r;
    const float bias = Bias[n];
    const float cz   = CZ[n];
    float* OutG = Out + (size_t)1024 * 1024;
    #pragma unroll
    for (int reg = 0; reg < 4; ++reg) {
        const int m = m0 + mt * 16 + q * 4 + reg;
        const float g   = expf(-(accG[reg] + cz));
        const float res = (accL[reg] + bias) * g;
        Out [(size_t)m * 1024 + n] = res;
        OutG[(size_t)m * 1024 + n] = g;
    }
}

extern "C" void kernel_launch(void* const* d_in, const int* in_sizes, int n_in,
                              void* d_out, int out_size, void* d_ws, size_t ws_size,
                              hipStream_t stream) {
    const float* X    = (const float*)d_in[0];
    const float* W    = (const float*)d_in[1];
    const float* Bias = (const float*)d_in[2];
    const float* C    = (const float*)d_in[3];
    const float* IC   = (const float*)d_in[4];
    float* Out = (float*)d_out;

    // workspace layout: 5 bf16 tensors [1024][256] (512 KB each) + cz (4 KB)
    unsigned short* XB  = (unsigned short*)d_ws;
    unsigned short* X2B = XB  + 262144;
    unsigned short* WB  = X2B + 262144;
    unsigned short* G1  = WB  + 262144;
    unsigned short* G2  = G1  + 262144;
    float*          CZ  = (float*)(G2 + 262144);

    fgn_prep<<<512, 256, 0, stream>>>(X, W, C, IC, XB, X2B, WB, G1, G2, CZ);
    fgn_main<<<512, 512, 0, stream>>>(XB, X2B, WB, G1, G2, Bias, CZ, Out);
}